// Round 2
// baseline (756.901 us; speedup 1.0000x reference)
//
#include <hip/hip_runtime.h>

// RegressionInstancesModule: ROI-align -> per-instance expert 3x3 convs ->
// (GAP->FC scale/shift) and (conv_c1->conv_c2->bilinear resize 14x14->480x640)
// All float I/O is float32 per the reference (round-1 NaN was the signature of
// misreading f32 as bf16: random low-half words decode to NaN at ~0.4% rate).

#define B_  4
#define N_  16
#define M_  64
#define H_  480
#define W_  640
#define HF  120
#define WF  160
#define C_  128
#define R_  14
#define PIX 196
#define NE  13

// workspace layout (float offsets)
#define WS_ROI   0
#define WS_H1    (WS_ROI + M_*C_*PIX)        // 1605632
#define WS_C     (WS_H1 + M_*64*PIX)         // 2408448
#define WS_GAP   (WS_C + M_*PIX)             // 2420992
#define WS_SCALE (WS_GAP + M_*C_)            // 2429184
#define WS_SHIFT (WS_SCALE + M_)             // 2429248
#define WS_WS_   (WS_SHIFT + M_)             // 2429312 (16B aligned)
#define WS_BS    (WS_WS_ + NE*8*C_*144)      // +1916928
#define WS_WFC   (WS_BS + NE*C_)
#define WS_BFC   (WS_WFC + NE*2*C_)
#define WS_WC1   (WS_BFC + 32)
#define WS_BC1   (WS_WC1 + NE*4*C_*144)      // +958464
#define WS_WC2   (WS_BC1 + NE*64)
#define WS_BC2   (WS_WC2 + NE*64*9)

__global__ __launch_bounds__(256) void prep_weights_kernel(
    const float* __restrict__ w_s, const float* __restrict__ b_s,
    const float* __restrict__ w_fc, const float* __restrict__ b_fc,
    const float* __restrict__ w_c1, const float* __restrict__ b_c1,
    const float* __restrict__ w_c2, const float* __restrict__ b_c2,
    float* __restrict__ ws)
{
  const int N0 = NE*8*C_*144;   // w_s permuted: [e][ocg8][ic128][j16*9]
  const int N1 = NE*4*C_*144;   // w_c1 permuted: [e][ocg4][ic128][j16*9]
  const int N2 = NE*64*9;       // w_c2 direct
  const int N3 = NE*C_;         // b_s
  const int N4 = NE*64;         // b_c1
  const int N5 = NE;            // b_c2
  const int N6 = NE*2*C_;       // w_fc
  const int N7 = NE*2;          // b_fc
  int total = N0+N1+N2+N3+N4+N5+N6+N7;
  for (int idx = blockIdx.x*256 + threadIdx.x; idx < total; idx += gridDim.x*256) {
    int d = idx;
    if (d < N0) {
      int k = d % 9; int r = d / 9;
      int j = r % 16; r /= 16;
      int ic = r % C_; r /= C_;
      int ocg = r % 8; int e = r / 8;
      int src = ((e*C_ + ocg*16 + j)*C_ + ic)*9 + k;
      ws[WS_WS_ + d] = w_s[src];
      continue;
    }
    d -= N0;
    if (d < N1) {
      int k = d % 9; int r = d / 9;
      int j = r % 16; r /= 16;
      int ic = r % C_; r /= C_;
      int ocg = r % 4; int e = r / 4;
      int src = ((e*64 + ocg*16 + j)*C_ + ic)*9 + k;
      ws[WS_WC1 + d] = w_c1[src];
      continue;
    }
    d -= N1;
    if (d < N2) { ws[WS_WC2 + d] = w_c2[d]; continue; }
    d -= N2;
    if (d < N3) { ws[WS_BS + d] = b_s[d]; continue; }
    d -= N3;
    if (d < N4) { ws[WS_BC1 + d] = b_c1[d]; continue; }
    d -= N4;
    if (d < N5) { ws[WS_BC2 + d] = b_c2[d]; continue; }
    d -= N5;
    if (d < N6) { ws[WS_WFC + d] = w_fc[d]; continue; }
    d -= N6;
    ws[WS_BFC + d] = b_fc[d];
  }
}

__global__ __launch_bounds__(256) void roi_align_kernel(
    const float* __restrict__ fmap, const float* __restrict__ boxes,
    float* __restrict__ ws)
{
  __shared__ int iy0[R_], ix0[R_];
  __shared__ float swy[R_], swx[R_];
  int m = blockIdx.x;
  int tid = threadIdx.x;
  if (tid < 2*R_) {
    int r = tid % R_;
    bool isY = tid < R_;
    float b0 = boxes[m*4 + (isY ? 0 : 1)];
    float b2 = boxes[m*4 + (isY ? 2 : 3)];
    float lo = 0.6f * b0;
    float hi = lo + 0.1f + 0.3f * b2;
    float t = ((float)r + 0.5f) / (float)R_;
    float dim = isY ? (float)(HF-1) : (float)(WF-1);
    float s = (lo + (hi - lo) * t) * dim;
    int maxi = isY ? (HF-2) : (WF-2);
    int i0 = (int)floorf(s);
    i0 = i0 < 0 ? 0 : (i0 > maxi ? maxi : i0);
    float w = s - (float)i0;
    w = w < 0.f ? 0.f : (w > 1.f ? 1.f : w);
    if (isY) { iy0[r] = i0; swy[r] = w; } else { ix0[r] = i0; swx[r] = w; }
  }
  __syncthreads();
  int bi = m / N_;
  const float* fb = fmap + (size_t)bi * C_ * HF * WF;
  float* roi = ws + WS_ROI + (size_t)m * C_ * PIX;
  for (int idx = tid; idx < C_*PIX; idx += 256) {
    int c = idx / PIX, p = idx % PIX;
    int ry = p / R_, rx = p % R_;
    int y0 = iy0[ry], x0 = ix0[rx];
    float wy = swy[ry], wx = swx[rx];
    const float* f = fb + ((size_t)c*HF + y0)*WF + x0;
    float f00 = f[0],  f01 = f[1];
    float f10 = f[WF], f11 = f[WF+1];
    roi[idx] = f00*(1.f-wy)*(1.f-wx) + f01*(1.f-wy)*wx
             + f10*wy*(1.f-wx)       + f11*wy*wx;
  }
}

// Generic 3x3 SAME conv over 14x14, per-instance expert weights.
// src: [M][IC][196] f32 (ws). w: [NE][OC/OCB][IC][OCB*9] f32 (wave-uniform
// reads -> scalar loads). out: gap [M][OC] (DO_GAP) or [M][OC][196].
template<int IC, int OC, int OCB, bool RELU, bool DO_GAP>
__global__ __launch_bounds__(256) void conv3_kernel(
    const float* __restrict__ src, const float* __restrict__ w,
    const float* __restrict__ bias, const int* __restrict__ labels,
    float* __restrict__ out)
{
  constexpr int NOCG = OC / OCB;
  constexpr int ICT = 32;
  __shared__ float tile[ICT * 256];   // 32 channels, padded 16x16, zero halo
  int m = blockIdx.x / NOCG;
  int ocg = blockIdx.x % NOCG;
  int e = labels[m];
  int tid = threadIdx.x;
  for (int i = tid; i < ICT*256; i += 256) tile[i] = 0.f;
  int p = tid < PIX ? tid : 0;
  int ry = p / R_, rx = p % R_;
  int tb = ry*16 + rx;               // top-left of 3x3 window in padded tile
  float acc[OCB];
  #pragma unroll
  for (int j = 0; j < OCB; ++j) acc[j] = 0.f;
  const float* srcm = src + (size_t)m * IC * PIX;
  const float* wb = w + (size_t)(e*NOCG + ocg) * IC * (OCB*9);

  for (int ict = 0; ict < IC; ict += ICT) {
    __syncthreads();
    for (int i = tid; i < ICT*PIX; i += 256) {
      int tc = i / PIX, pp = i % PIX;
      int py = pp / R_, px = pp % R_;
      tile[tc*256 + (py+1)*16 + (px+1)] = srcm[(ict+tc)*PIX + pp];
    }
    __syncthreads();
    #pragma unroll 4
    for (int tc = 0; tc < ICT; ++tc) {
      const float* t = tile + tc*256 + tb;
      float v0=t[0],  v1=t[1],  v2=t[2];
      float v3=t[16], v4=t[17], v5=t[18];
      float v6=t[32], v7=t[33], v8=t[34];
      const float* wp = wb + (size_t)(ict+tc) * (OCB*9);
      #pragma unroll
      for (int j = 0; j < OCB; ++j) {
        const float* wj = wp + j*9;
        acc[j] += v0*wj[0] + v1*wj[1] + v2*wj[2]
                + v3*wj[3] + v4*wj[4] + v5*wj[5]
                + v6*wj[6] + v7*wj[7] + v8*wj[8];
      }
    }
  }
  #pragma unroll
  for (int j = 0; j < OCB; ++j) {
    float hv = acc[j] + bias[e*OC + ocg*OCB + j];
    if (RELU) hv = hv > 0.f ? hv : 0.f;
    acc[j] = hv;
  }
  if (DO_GAP) {
    if (tid >= PIX) {
      #pragma unroll
      for (int j = 0; j < OCB; ++j) acc[j] = 0.f;
    }
    __syncthreads();   // tile reused as reduction scratch
    #pragma unroll
    for (int j = 0; j < OCB; ++j) {
      float s = acc[j];
      for (int off = 32; off > 0; off >>= 1) s += __shfl_down(s, off);
      if ((tid & 63) == 0) tile[j*4 + (tid >> 6)] = s;
    }
    __syncthreads();
    if (tid < OCB) {
      float s = tile[tid*4] + tile[tid*4+1] + tile[tid*4+2] + tile[tid*4+3];
      out[(size_t)m*OC + ocg*OCB + tid] = s * (1.f/(float)PIX);
    }
  } else {
    if (tid < PIX) {
      #pragma unroll
      for (int j = 0; j < OCB; ++j)
        out[((size_t)m*OC + ocg*OCB + j)*PIX + p] = acc[j];
    }
  }
}

__global__ __launch_bounds__(128) void fc_kernel(
    const float* __restrict__ gap, const float* __restrict__ wfc,
    const float* __restrict__ bfc, const int* __restrict__ labels,
    float* __restrict__ ws_scale, float* __restrict__ ws_shift,
    float* __restrict__ out)
{
  int t = threadIdx.x;
  int m = t >> 1, o = t & 1;
  int e = labels[m];
  const float* g = gap + m*C_;
  const float* wv = wfc + (e*2 + o)*C_;
  float s = bfc[e*2 + o];
  for (int c = 0; c < C_; ++c) s += g[c] * wv[c];
  size_t base = (size_t)2 * M_ * H_ * W_;
  if (o == 0) { ws_scale[m] = s; out[base + m] = s; }
  else        { ws_shift[m] = s; out[base + M_ + m] = s; }
}

// jax.image.resize bilinear 14x14 -> 480x640 (half-pixel centers, edge
// renormalization == coordinate clamp for upsampling), + affine + floor.
__global__ __launch_bounds__(256) void resize_kernel(
    const float* __restrict__ ws_c, const float* __restrict__ ws_scale,
    const float* __restrict__ ws_shift, float* __restrict__ out)
{
  __shared__ float cs[PIX];
  int bx = blockIdx.x;
  int m = bx / 150;
  int chunk = bx % 150;
  int tid = threadIdx.x;
  if (tid < PIX) cs[tid] = ws_c[m*PIX + tid];
  __syncthreads();
  float sc = ws_scale[m], sh = ws_shift[m];
  int q0 = chunk*2048 + tid*8;          // 8 consecutive x, same y (640%8==0)
  int y = q0 / W_;
  int x0i = q0 - y*W_;
  float py = ((float)y + 0.5f) * (14.f/(float)H_) - 0.5f;
  py = fminf(fmaxf(py, 0.f), 13.f);
  int y0 = (int)py; y0 = y0 > 12 ? 12 : y0;
  float wy = py - (float)y0;
  const float* r0 = cs + y0*R_;
  const float* r1 = r0 + R_;
  float vd[8], vc[8];
  #pragma unroll
  for (int u = 0; u < 8; ++u) {
    int x = x0i + u;
    float px = ((float)x + 0.5f) * (14.f/(float)W_) - 0.5f;
    px = fminf(fmaxf(px, 0.f), 13.f);
    int xq = (int)px; xq = xq > 12 ? 12 : xq;
    float wx = px - (float)xq;
    float v = (r0[xq]*(1.f-wx) + r0[xq+1]*wx) * (1.f-wy)
            + (r1[xq]*(1.f-wx) + r1[xq+1]*wx) * wy;
    vc[u] = v;
    vd[u] = fmaxf(v*sc + sh, 0.001f);
  }
  size_t base = (size_t)m * H_ * W_ + q0;
  float* od = out + base;
  float* oc = out + (size_t)M_*H_*W_ + base;
  *(float4*)(od)     = make_float4(vd[0], vd[1], vd[2], vd[3]);
  *(float4*)(od + 4) = make_float4(vd[4], vd[5], vd[6], vd[7]);
  *(float4*)(oc)     = make_float4(vc[0], vc[1], vc[2], vc[3]);
  *(float4*)(oc + 4) = make_float4(vc[4], vc[5], vc[6], vc[7]);
}

extern "C" void kernel_launch(void* const* d_in, const int* in_sizes, int n_in,
                              void* d_out, int out_size, void* d_ws, size_t ws_size,
                              hipStream_t stream) {
  const float* fmap  = (const float*)d_in[2];   // input_feature_map (4,128,120,160)
  const float* boxes = (const float*)d_in[8];   // (4,16,4)
  const int* labels  = (const int*)d_in[9];     // (4,16)
  const float* w_s  = (const float*)d_in[10];
  const float* b_s  = (const float*)d_in[11];
  const float* w_fc = (const float*)d_in[12];
  const float* b_fc = (const float*)d_in[13];
  const float* w_c1 = (const float*)d_in[14];
  const float* b_c1 = (const float*)d_in[15];
  const float* w_c2 = (const float*)d_in[16];
  const float* b_c2 = (const float*)d_in[17];
  float* ws = (float*)d_ws;
  float* out = (float*)d_out;

  hipLaunchKernelGGL(prep_weights_kernel, dim3(2048), dim3(256), 0, stream,
                     w_s, b_s, w_fc, b_fc, w_c1, b_c1, w_c2, b_c2, ws);
  hipLaunchKernelGGL(roi_align_kernel, dim3(M_), dim3(256), 0, stream,
                     fmap, boxes, ws);
  hipLaunchKernelGGL((conv3_kernel<C_, C_, 16, true, true>), dim3(M_*8), dim3(256), 0, stream,
                     ws + WS_ROI, ws + WS_WS_, ws + WS_BS, labels, ws + WS_GAP);
  hipLaunchKernelGGL(fc_kernel, dim3(1), dim3(128), 0, stream,
                     ws + WS_GAP, ws + WS_WFC, ws + WS_BFC, labels,
                     ws + WS_SCALE, ws + WS_SHIFT, out);
  hipLaunchKernelGGL((conv3_kernel<C_, 64, 16, true, false>), dim3(M_*4), dim3(256), 0, stream,
                     ws + WS_ROI, ws + WS_WC1, ws + WS_BC1, labels, ws + WS_H1);
  hipLaunchKernelGGL((conv3_kernel<64, 1, 1, false, false>), dim3(M_), dim3(256), 0, stream,
                     ws + WS_H1, ws + WS_WC2, ws + WS_BC2, labels, ws + WS_C);
  hipLaunchKernelGGL(resize_kernel, dim3(M_*150), dim3(256), 0, stream,
                     ws + WS_C, ws + WS_SCALE, ws + WS_SHIFT, out);
}

// Round 3
// 390.860 us; speedup vs baseline: 1.9365x; 1.9365x over previous
//
#include <hip/hip_runtime.h>

// RegressionInstancesModule on gfx950.
// R3: conv_s+conv_c1 fused into one bf16-MFMA batched GEMM (K=9 taps x 128 ic,
// B staged from transposed bf16 ROI with shift+zero-border at staging time;
// no im2col materialization). GAP fused into GEMM epilogue. conv_c2 = small
// LDS VALU kernel. R2 conv kernels were VMEM-issue-bound (per-FMA broadcast
// weight loads, VALUBusy 23%, 2 blocks/CU).

typedef unsigned short bfu;
typedef __attribute__((ext_vector_type(8))) short bf16x8;
typedef __attribute__((ext_vector_type(4))) float f32x4;

__device__ __forceinline__ float bf2f(bfu u) {
  union { unsigned int i; float f; } v;
  v.i = ((unsigned int)u) << 16;
  return v.f;
}
__device__ __forceinline__ bfu f2bf(float f) {
  union { float f; unsigned int i; } v;
  v.f = f;
  unsigned int u = v.i;
  u = (u + 0x7fffu + ((u >> 16) & 1u)) >> 16;
  return (bfu)u;
}

#define B_  4
#define N_  16
#define M_  64
#define H_  480
#define W_  640
#define HF  120
#define WF  160
#define C_  128
#define R_  14
#define PIX 196
#define NE  13
#define KK  1152   // 9*128

// workspace layout (float offsets); total ~2.68M floats (10.7 MB)
#define WS_XB    0                         // bf16 Xb[64][196][128]
#define WS_XH    802816                    // bf16 Xh[64][196][64]
#define WS_C     1204224                   // f32 c[64][196]
#define WS_GAP   1216768                   // f32 gap[64][128] (sums; zeroed)
#define WS_SCALE 1224960                   // f32 [64]
#define WS_SHIFT 1225024                   // f32 [64]
#define WS_WF    1225088                   // bf16 WF[13][192][1152], k=kidx*128+ic
#define WS_BIASF 2662784                   // f32 [13][192]
#define WS_W2    2665280                   // f32 [13][576], idx=kidx*64+ic
#define WS_B2    2672768                   // f32 [13] (pad 16)
#define WS_WFC   2672784                   // f32 [13][2][128]
#define WS_BFC   2676112                   // f32 [13][2] (pad 32)

// ---------------- prep: weights -> bf16 GEMM layout, zero gap ----------------
__global__ __launch_bounds__(256) void prep_kernel(
    const float* __restrict__ w_s, const float* __restrict__ b_s,
    const float* __restrict__ w_fc, const float* __restrict__ b_fc,
    const float* __restrict__ w_c1, const float* __restrict__ b_c1,
    const float* __restrict__ w_c2, const float* __restrict__ b_c2,
    float* __restrict__ ws)
{
  const int P0 = NE*192*KK;     // WF bf16
  const int P1 = NE*192;        // biasf
  const int P2 = NE*576;        // w2
  const int P3 = NE;            // b2
  const int P4 = NE*256;        // wfc
  const int P5 = NE*2;          // bfc
  const int P6 = M_*C_;         // gap zero
  int total = P0+P1+P2+P3+P4+P5+P6;
  bfu* wf = (bfu*)(ws + WS_WF);
  for (int idx = blockIdx.x*256 + threadIdx.x; idx < total; idx += gridDim.x*256) {
    int d = idx;
    if (d < P0) {
      int e = d / (192*KK);
      int r = d - e*(192*KK);
      int oc = r / KK;
      int k  = r - oc*KK;
      int kidx = k >> 7, ic = k & 127;
      float v = (oc < 128) ? w_s[((e*128 + oc)*128 + ic)*9 + kidx]
                           : w_c1[((e*64 + (oc-128))*128 + ic)*9 + kidx];
      wf[d] = f2bf(v);
      continue;
    }
    d -= P0;
    if (d < P1) {
      int e = d / 192, oc = d - e*192;
      ws[WS_BIASF + d] = (oc < 128) ? b_s[e*128 + oc] : b_c1[e*64 + oc - 128];
      continue;
    }
    d -= P1;
    if (d < P2) {
      int e = d / 576, k = d - e*576;
      int kidx = k >> 6, ic = k & 63;
      ws[WS_W2 + d] = w_c2[(e*64 + ic)*9 + kidx];
      continue;
    }
    d -= P2;
    if (d < P3) { ws[WS_B2 + d] = b_c2[d]; continue; }
    d -= P3;
    if (d < P4) { ws[WS_WFC + d] = w_fc[d]; continue; }
    d -= P4;
    if (d < P5) { ws[WS_BFC + d] = b_fc[d]; continue; }
    d -= P5;
    ws[WS_GAP + d] = 0.f;
  }
}

// ---------------- ROI-align -> transposed bf16 Xb[m][p][ic] ----------------
__global__ __launch_bounds__(256) void xb_kernel(
    const float* __restrict__ fmap, const float* __restrict__ boxes,
    float* __restrict__ ws)
{
  __shared__ int iy0[R_], ix0[R_];
  __shared__ float swy[R_], swx[R_];
  int m = blockIdx.x;
  int tid = threadIdx.x;
  if (tid < 2*R_) {
    int r = tid % R_;
    bool isY = tid < R_;
    float b0 = boxes[m*4 + (isY ? 0 : 1)];
    float b2 = boxes[m*4 + (isY ? 2 : 3)];
    float lo = 0.6f * b0;
    float hi = lo + 0.1f + 0.3f * b2;
    float t = ((float)r + 0.5f) / (float)R_;
    float dim = isY ? (float)(HF-1) : (float)(WF-1);
    float s = (lo + (hi - lo) * t) * dim;
    int maxi = isY ? (HF-2) : (WF-2);
    int i0 = (int)floorf(s);
    i0 = i0 < 0 ? 0 : (i0 > maxi ? maxi : i0);
    float w = s - (float)i0;
    w = w < 0.f ? 0.f : (w > 1.f ? 1.f : w);
    if (isY) { iy0[r] = i0; swy[r] = w; } else { ix0[r] = i0; swx[r] = w; }
  }
  __syncthreads();
  int bi = m / N_;
  const float* fb = fmap + (size_t)bi * C_ * HF * WF;
  bfu* xb = (bfu*)(ws + WS_XB);
  for (int idx = tid; idx < PIX*64; idx += 256) {
    int ic2 = (idx & 63) * 2;
    int p = idx >> 6;
    int ry = p / R_, rx = p - (p/R_)*R_;
    int y0 = iy0[ry], x0 = ix0[rx];
    float wy = swy[ry], wx = swx[rx];
    float w00 = (1.f-wy)*(1.f-wx), w01 = (1.f-wy)*wx;
    float w10 = wy*(1.f-wx),       w11 = wy*wx;
    bfu pk[2];
    #pragma unroll
    for (int u = 0; u < 2; ++u) {
      const float* f = fb + ((size_t)(ic2+u)*HF + y0)*WF + x0;
      float v = f[0]*w00 + f[1]*w01 + f[WF]*w10 + f[WF+1]*w11;
      pk[u] = f2bf(v);
    }
    *(ushort2*)&xb[((size_t)m*PIX + p)*128 + ic2] = make_ushort2(pk[0], pk[1]);
  }
}

// ---------------- fused GEMM: [192oc x 208pix] = WF x im2col(Xb) ----------------
// block: 256 thr = 4 waves; tile 128M x 128N; grid = 64 inst * 2 mb * 2 nb.
// K-loop: 36 steps of 32 (kidx 0..8 x ic-chunk 0..3); B staged with tap shift.
__global__ __launch_bounds__(256) void gemm_kernel(
    const int* __restrict__ labels, float* __restrict__ ws)
{
  __shared__ bfu lA[128*32];
  __shared__ bfu lB[128*32];
  const bfu* Xb = (const bfu*)(ws + WS_XB);
  const bfu* WFp = (const bfu*)(ws + WS_WF);
  const float* biasf = ws + WS_BIASF;
  float* gap = ws + WS_GAP;
  bfu* Xh = (bfu*)(ws + WS_XH);

  int bx = blockIdx.x;
  int m  = bx >> 2;
  int mb = (bx >> 1) & 1;
  int nb = bx & 1;
  int e = labels[m];
  int tid = threadIdx.x;
  int wave = tid >> 6, lane = tid & 63;
  int wm = wave >> 1, wn = wave & 1;
  int l15 = lane & 15, q = lane >> 4;

  // staging: chunk c = tid -> row=c>>2 (0..63), c=tid+256 -> row 64..127; kc=c&3
  int row0 = tid >> 2, row1 = row0 + 64;
  int kc = tid & 3;
  int loff0 = row0*32 + (kc ^ ((row0 >> 1) & 3))*8;   // swizzled lds offset (ushorts)
  int loff1 = row1*32 + (kc ^ ((row1 >> 1) & 3))*8;
  // A global rows
  int g0 = mb*128 + row0, g1 = mb*128 + row1;
  bool av0 = g0 < 192, av1 = g1 < 192;
  const bfu* wfe = WFp + (size_t)e*192*KK;
  const bfu* wr0 = wfe + (size_t)g0*KK + kc*8;
  const bfu* wr1 = wfe + (size_t)g1*KK + kc*8;
  // B pixel rows
  int pg0 = nb*128 + row0, pg1 = nb*128 + row1;
  int py0 = pg0 / 14, px0 = pg0 - (pg0/14)*14;
  int py1 = pg1 / 14, px1 = pg1 - (pg1/14)*14;
  bool pv0 = pg0 < PIX, pv1 = pg1 < PIX;
  const bfu* xbm = Xb + (size_t)m*PIX*128;

  f32x4 acc[4][4];
  #pragma unroll
  for (int i = 0; i < 4; ++i)
    #pragma unroll
    for (int j = 0; j < 4; ++j)
      acc[i][j] = (f32x4){0.f, 0.f, 0.f, 0.f};

  const uint4 z4 = make_uint4(0,0,0,0);
  for (int s = 0; s < 36; ++s) {
    int kidx = s >> 2, icc = s & 3;
    int dy = kidx/3 - 1, dx = (kidx - (kidx/3)*3) - 1;
    uint4 a0 = av0 ? *(const uint4*)(wr0 + s*32) : z4;
    uint4 a1 = av1 ? *(const uint4*)(wr1 + s*32) : z4;
    int ys0 = py0 + dy, xs0 = px0 + dx;
    int ys1 = py1 + dy, xs1 = px1 + dx;
    bool v0 = pv0 && (unsigned)ys0 < 14u && (unsigned)xs0 < 14u;
    bool v1 = pv1 && (unsigned)ys1 < 14u && (unsigned)xs1 < 14u;
    uint4 b0 = v0 ? *(const uint4*)(xbm + (size_t)(ys0*14+xs0)*128 + icc*32 + kc*8) : z4;
    uint4 b1 = v1 ? *(const uint4*)(xbm + (size_t)(ys1*14+xs1)*128 + icc*32 + kc*8) : z4;
    __syncthreads();
    *(uint4*)&lA[loff0] = a0;
    *(uint4*)&lA[loff1] = a1;
    *(uint4*)&lB[loff0] = b0;
    *(uint4*)&lB[loff1] = b1;
    __syncthreads();
    bf16x8 af[4], bfr[4];
    #pragma unroll
    for (int i = 0; i < 4; ++i) {
      int r = wm*64 + i*16 + l15;
      af[i] = *(const bf16x8*)&lA[r*32 + (q ^ ((r >> 1) & 3))*8];
    }
    #pragma unroll
    for (int j = 0; j < 4; ++j) {
      int r = wn*64 + j*16 + l15;
      bfr[j] = *(const bf16x8*)&lB[r*32 + (q ^ ((r >> 1) & 3))*8];
    }
    #pragma unroll
    for (int i = 0; i < 4; ++i)
      #pragma unroll
      for (int j = 0; j < 4; ++j)
        acc[i][j] = __builtin_amdgcn_mfma_f32_16x16x32_bf16(af[i], bfr[j], acc[i][j], 0, 0, 0);
  }

  // epilogue: C row = oc (quad*4+reg within 16-tile), col = pix (lane&15)
  if (mb == 0) {
    // all rows are hs -> bias+relu, masked sum over pix, atomic into gap sums
    #pragma unroll
    for (int i = 0; i < 4; ++i) {
      int ocb = wm*64 + i*16 + q*4;
      f32x4 bv = *(const f32x4*)&biasf[e*192 + ocb];
      #pragma unroll
      for (int r = 0; r < 4; ++r) {
        float sum = 0.f;
        #pragma unroll
        for (int j = 0; j < 4; ++j) {
          int p = nb*128 + wn*64 + j*16 + l15;
          float v = acc[i][j][r] + bv[r];
          v = v > 0.f ? v : 0.f;
          if (p < PIX) sum += v;
        }
        sum += __shfl_xor(sum, 1);
        sum += __shfl_xor(sum, 2);
        sum += __shfl_xor(sum, 4);
        sum += __shfl_xor(sum, 8);
        if (l15 == 0) atomicAdd(&gap[m*C_ + ocb + r], sum);
      }
    }
  } else if (wm == 0) {
    // rows 128..191 -> h1, store bf16 Xh[m][p][ic] (ic = row-128)
    #pragma unroll
    for (int i = 0; i < 4; ++i) {
      int icb = i*16 + q*4;
      f32x4 bv = *(const f32x4*)&biasf[e*192 + 128 + icb];
      #pragma unroll
      for (int j = 0; j < 4; ++j) {
        int p = nb*128 + wn*64 + j*16 + l15;
        if (p < PIX) {
          ushort4 pk;
          float v0 = acc[i][j][0] + bv[0]; v0 = v0 > 0.f ? v0 : 0.f;
          float v1 = acc[i][j][1] + bv[1]; v1 = v1 > 0.f ? v1 : 0.f;
          float v2 = acc[i][j][2] + bv[2]; v2 = v2 > 0.f ? v2 : 0.f;
          float v3 = acc[i][j][3] + bv[3]; v3 = v3 > 0.f ? v3 : 0.f;
          pk.x = f2bf(v0); pk.y = f2bf(v1); pk.z = f2bf(v2); pk.w = f2bf(v3);
          *(ushort4*)&Xh[((size_t)m*PIX + p)*64 + icb] = pk;
        }
      }
    }
  }
}

// ---------------- FC: scale/shift from gap sums ----------------
__global__ __launch_bounds__(128) void fc_kernel(
    const int* __restrict__ labels, float* __restrict__ ws,
    float* __restrict__ out)
{
  int t = threadIdx.x;
  int m = t >> 1, o = t & 1;
  int e = labels[m];
  const float* g = ws + WS_GAP + m*C_;
  const float* wv = ws + WS_WFC + (e*2 + o)*C_;
  float s = 0.f;
  for (int c = 0; c < C_; ++c) s += g[c] * wv[c];
  s = ws[WS_BFC + e*2 + o] + s * (1.f/(float)PIX);
  size_t base = (size_t)2 * M_ * H_ * W_;
  if (o == 0) { ws[WS_SCALE + m] = s; out[base + m] = s; }
  else        { ws[WS_SHIFT + m] = s; out[base + M_ + m] = s; }
}

// ---------------- conv_c2: 3x3, 64ch -> 1, from bf16 Xh ----------------
__global__ __launch_bounds__(256) void convc2_kernel(
    const int* __restrict__ labels, float* __restrict__ ws)
{
  __shared__ bfu xh[PIX*64];
  __shared__ float w2l[576];
  int m = blockIdx.x;
  int e = labels[m];
  int tid = threadIdx.x;
  const bfu* Xh = (const bfu*)(ws + WS_XH) + (size_t)m*PIX*64;
  for (int i = tid; i < PIX*64/8; i += 256)
    *(uint4*)&xh[i*8] = *(const uint4*)&Xh[i*8];
  for (int i = tid; i < 576; i += 256)
    w2l[i] = ws[WS_W2 + e*576 + i];
  __syncthreads();
  if (tid < PIX) {
    int y = tid / 14, x = tid - (tid/14)*14;
    float acc = 0.f;
    #pragma unroll
    for (int kidx = 0; kidx < 9; ++kidx) {
      int ys = y + kidx/3 - 1, xs = x + (kidx - (kidx/3)*3) - 1;
      if ((unsigned)ys < 14u && (unsigned)xs < 14u) {
        const bfu* xr = xh + (ys*14 + xs)*64;
        const float* wr = w2l + kidx*64;
        #pragma unroll
        for (int cc = 0; cc < 8; ++cc) {
          bf16x8 xv = *(const bf16x8*)&xr[cc*8];
          f32x4 wa = *(const f32x4*)&wr[cc*8];
          f32x4 wb = *(const f32x4*)&wr[cc*8 + 4];
          acc += bf2f((bfu)xv[0])*wa[0] + bf2f((bfu)xv[1])*wa[1]
               + bf2f((bfu)xv[2])*wa[2] + bf2f((bfu)xv[3])*wa[3]
               + bf2f((bfu)xv[4])*wb[0] + bf2f((bfu)xv[5])*wb[1]
               + bf2f((bfu)xv[6])*wb[2] + bf2f((bfu)xv[7])*wb[3];
        }
      }
    }
    ws[WS_C + m*PIX + tid] = acc + ws[WS_B2 + e];
  }
}

// ---------------- bilinear resize 14x14 -> 480x640 + affine ----------------
__global__ __launch_bounds__(256) void resize_kernel(
    const float* __restrict__ ws_c, const float* __restrict__ ws_scale,
    const float* __restrict__ ws_shift, float* __restrict__ out)
{
  __shared__ float cs[PIX];
  int bx = blockIdx.x;
  int m = bx / 150;
  int chunk = bx % 150;
  int tid = threadIdx.x;
  if (tid < PIX) cs[tid] = ws_c[m*PIX + tid];
  __syncthreads();
  float sc = ws_scale[m], sh = ws_shift[m];
  int q0 = chunk*2048 + tid*8;
  int y = q0 / W_;
  int x0i = q0 - y*W_;
  float py = ((float)y + 0.5f) * (14.f/(float)H_) - 0.5f;
  py = fminf(fmaxf(py, 0.f), 13.f);
  int y0 = (int)py; y0 = y0 > 12 ? 12 : y0;
  float wy = py - (float)y0;
  const float* r0 = cs + y0*R_;
  const float* r1 = r0 + R_;
  float vd[8], vc[8];
  #pragma unroll
  for (int u = 0; u < 8; ++u) {
    int x = x0i + u;
    float px = ((float)x + 0.5f) * (14.f/(float)W_) - 0.5f;
    px = fminf(fmaxf(px, 0.f), 13.f);
    int xq = (int)px; xq = xq > 12 ? 12 : xq;
    float wx = px - (float)xq;
    float v = (r0[xq]*(1.f-wx) + r0[xq+1]*wx) * (1.f-wy)
            + (r1[xq]*(1.f-wx) + r1[xq+1]*wx) * wy;
    vc[u] = v;
    vd[u] = fmaxf(v*sc + sh, 0.001f);
  }
  size_t base = (size_t)m * H_ * W_ + q0;
  float* od = out + base;
  float* oc = out + (size_t)M_*H_*W_ + base;
  *(float4*)(od)     = make_float4(vd[0], vd[1], vd[2], vd[3]);
  *(float4*)(od + 4) = make_float4(vd[4], vd[5], vd[6], vd[7]);
  *(float4*)(oc)     = make_float4(vc[0], vc[1], vc[2], vc[3]);
  *(float4*)(oc + 4) = make_float4(vc[4], vc[5], vc[6], vc[7]);
}

extern "C" void kernel_launch(void* const* d_in, const int* in_sizes, int n_in,
                              void* d_out, int out_size, void* d_ws, size_t ws_size,
                              hipStream_t stream) {
  const float* fmap  = (const float*)d_in[2];
  const float* boxes = (const float*)d_in[8];
  const int* labels  = (const int*)d_in[9];
  const float* w_s  = (const float*)d_in[10];
  const float* b_s  = (const float*)d_in[11];
  const float* w_fc = (const float*)d_in[12];
  const float* b_fc = (const float*)d_in[13];
  const float* w_c1 = (const float*)d_in[14];
  const float* b_c1 = (const float*)d_in[15];
  const float* w_c2 = (const float*)d_in[16];
  const float* b_c2 = (const float*)d_in[17];
  float* ws = (float*)d_ws;
  float* out = (float*)d_out;

  hipLaunchKernelGGL(prep_kernel, dim3(1024), dim3(256), 0, stream,
                     w_s, b_s, w_fc, b_fc, w_c1, b_c1, w_c2, b_c2, ws);
  hipLaunchKernelGGL(xb_kernel, dim3(M_), dim3(256), 0, stream,
                     fmap, boxes, ws);
  hipLaunchKernelGGL(gemm_kernel, dim3(M_*4), dim3(256), 0, stream,
                     labels, ws);
  hipLaunchKernelGGL(fc_kernel, dim3(1), dim3(128), 0, stream,
                     labels, ws, out);
  hipLaunchKernelGGL(convc2_kernel, dim3(M_), dim3(256), 0, stream,
                     labels, ws);
  hipLaunchKernelGGL(resize_kernel, dim3(M_*150), dim3(256), 0, stream,
                     ws + WS_C, ws + WS_SCALE, ws + WS_SHIFT, out);
}